// Round 2
// baseline (49.649 us; speedup 1.0000x reference)
//
#include <hip/hip_runtime.h>
#include <hip/hip_bf16.h>

typedef __attribute__((ext_vector_type(8)))  short    short8;
typedef __attribute__((ext_vector_type(16))) float    f32x16;
typedef __attribute__((ext_vector_type(4)))  unsigned uint4v;

#define K_DIM   4096
#define N_DIM   16384
#define WORDS_N 512

// Decode two ternary weights (bits at position b of words A0/A1 = nonzero,
// S0/S1 = sign) into one dword holding two packed bf16 values {-1,0,+1}.
// bf16(+1)=0x3F80, bf16(-1)=0xBF80; nz=0,sg=1 yields 0x8000 = -0.0 (harmless).
// r15/r31 are precomputed rotation amounts placing bit b at positions 15/31.
__device__ __forceinline__ unsigned dec2(unsigned A0, unsigned A1,
                                         unsigned S0, unsigned S1,
                                         int b, int r15, int r31) {
    unsigned r0   = (A0 >> b) & 1u;                    // v_bfe_u32
    unsigned r1   = (A1 >> b) & 1u;                    // v_bfe_u32
    unsigned mags = ((r1 * 0x3F80u) << 16) | (r0 * 0x3F80u);
    unsigned t0   = __builtin_amdgcn_alignbit(S0, S0, (unsigned)r15) & 0x8000u;
    unsigned t1   = __builtin_amdgcn_alignbit(S1, S1, (unsigned)r31) & 0x80000000u;
    return mags | t0 | t1;
}

// Truncate two fp32 (given as raw bits) to one dword of two packed bf16.
__device__ __forceinline__ unsigned pack_bf16(unsigned hi, unsigned lo) {
    return __builtin_amdgcn_perm(hi, lo, 0x07060302u);  // {hi.b3,hi.b2,lo.b3,lo.b2}
}

__global__ __launch_bounds__(512)
void ternary_gemm_kernel(const unsigned* __restrict__ x,   // fp32 bits [32][4096]
                         const unsigned* __restrict__ Bnz,
                         const unsigned* __restrict__ Bsg,
                         const float* __restrict__ bias,
                         float* __restrict__ out)
{
    __shared__ unsigned sm_nz[K_DIM];      // 16 KB: bit-plane column (nonzero)
    __shared__ unsigned sm_sg[K_DIM];      // 16 KB: bit-plane column (sign)
    __shared__ float    red[8][1024];      // 32 KB: per-wave partial 32x32 tiles

    // XCD-bijective swizzle: round-robin dispatch -> contiguous wb per XCD,
    // so the 16 blocks sharing each 64B bit-plane line hit the same L2.
    const int bid = blockIdx.x;
    const int wb  = (bid & 7) * 64 + (bid >> 3);   // 512 blocks, 512%8==0

    const int tid = threadIdx.x;

    // Stage the wb-th word column of both planes (stride-WORDS_N gather; the
    // full 16 MB is compulsory traffic shared across blocks via L2/L3).
    #pragma unroll
    for (int i = 0; i < 8; ++i) {
        const int k = tid + i * 512;
        sm_nz[k] = Bnz[k * WORDS_N + wb];
        sm_sg[k] = Bsg[k * WORDS_N + wb];
    }
    __syncthreads();

    const int lane = tid & 63;
    const int wv   = tid >> 6;        // wave id 0..7: K-chunk owner
    const int h    = lane >> 5;       // half-wave -> which 8-k group
    const int b    = lane & 31;       // bit position == column within tile == A row
    const int r15  = (b + 17) & 31;   // rot amount: bit b -> pos 15
    const int r31  = (b + 1) & 31;    // rot amount: bit b -> pos 31
    const int kbase = wv * 512 + h * 8;

    const unsigned* xrow = x + (size_t)b * K_DIM + kbase;

    f32x16 acc{};

    #pragma unroll 4
    for (int s = 0; s < 32; ++s) {
        const int kk = kbase + s * 16;
        // broadcast reads: all 32 lanes of a half-wave read the same 16B
        uint4v nzA = *(const uint4v*)(sm_nz + kk);
        uint4v nzB = *(const uint4v*)(sm_nz + kk + 4);
        uint4v sgA = *(const uint4v*)(sm_sg + kk);
        uint4v sgB = *(const uint4v*)(sm_sg + kk + 4);

        // A fragment: x[m = lane&31][kk..kk+7] as fp32, truncate to bf16.
        uint4v a0 = *(const uint4v*)(xrow + s * 16);
        uint4v a1 = *(const uint4v*)(xrow + s * 16 + 4);
        union { unsigned u[4]; short8 v; } aa;
        aa.u[0] = pack_bf16(a0[1], a0[0]);
        aa.u[1] = pack_bf16(a0[3], a0[2]);
        aa.u[2] = pack_bf16(a1[1], a1[0]);
        aa.u[3] = pack_bf16(a1[3], a1[2]);

        union { unsigned u[4]; short8 v; } bb;
        bb.u[0] = dec2(nzA[0], nzA[1], sgA[0], sgA[1], b, r15, r31);
        bb.u[1] = dec2(nzA[2], nzA[3], sgA[2], sgA[3], b, r15, r31);
        bb.u[2] = dec2(nzB[0], nzB[1], sgB[0], sgB[1], b, r15, r31);
        bb.u[3] = dec2(nzB[2], nzB[3], sgB[2], sgB[3], b, r15, r31);

        acc = __builtin_amdgcn_mfma_f32_32x32x16_bf16(aa.v, bb.v, acc, 0, 0, 0);
    }

    // Write per-wave partial tile to LDS.
    // C/D layout (m74/m101): col = lane&31, row = (r&3) + 8*(r>>2) + 4*(lane>>5)
    #pragma unroll
    for (int r = 0; r < 16; ++r) {
        const int row = (r & 3) + 8 * (r >> 2) + 4 * h;
        red[wv][row * 32 + b] = acc[r];
    }
    __syncthreads();

    // 8-way K reduction + bias + ReLU + fp32 store. 2 outputs/thread.
    const int i0 = tid * 2;
    float s0 = 0.f, s1 = 0.f;
    #pragma unroll
    for (int r = 0; r < 8; ++r) {
        const float2 p = *(const float2*)&red[r][i0];
        s0 += p.x;
        s1 += p.y;
    }
    const int mm = i0 >> 5;           // output row 0..31
    const int nn = i0 & 31;           // column within tile (even)
    const float2 bs = *(const float2*)(bias + wb * 32 + nn);
    float y0 = s0 + bs.x; y0 = y0 < 0.f ? 0.f : y0;
    float y1 = s1 + bs.y; y1 = y1 < 0.f ? 0.f : y1;
    float2 yy; yy.x = y0; yy.y = y1;
    *(float2*)(out + (size_t)mm * N_DIM + wb * 32 + nn) = yy;
}

extern "C" void kernel_launch(void* const* d_in, const int* in_sizes, int n_in,
                              void* d_out, int out_size, void* d_ws, size_t ws_size,
                              hipStream_t stream) {
    const unsigned* x   = (const unsigned*)d_in[0];   // fp32 bits
    const unsigned* nz  = (const unsigned*)d_in[1];
    const unsigned* sg  = (const unsigned*)d_in[2];
    const float* bias   = (const float*)d_in[3];
    float* out          = (float*)d_out;

    ternary_gemm_kernel<<<512, 512, 0, stream>>>(x, nz, sg, bias, out);
}

// Round 3
// 35.085 us; speedup vs baseline: 1.4151x; 1.4151x over previous
//
#include <hip/hip_runtime.h>
#include <hip/hip_bf16.h>

typedef __attribute__((ext_vector_type(8)))  short    short8;
typedef __attribute__((ext_vector_type(16))) float    f32x16;
typedef __attribute__((ext_vector_type(4)))  unsigned uint4v;

#define K_DIM    4096
#define N_DIM    16384
#define WORDS_N  512
#define NT_WORDS 16      // 512 output columns per block
#define KCH      128     // k-chunk staged per double-buffer step
#define BROW     132     // padded LDS row stride for B planes (words)

// Decode two ternary weights (bit b of words A0/A1 = nonzero, S0/S1 = sign)
// into one dword of two packed bf16 {-1,0,+1}. nz=0,sg=1 -> -0.0 (harmless).
__device__ __forceinline__ unsigned dec2(unsigned A0, unsigned A1,
                                         unsigned S0, unsigned S1,
                                         int b, int r15, int r31) {
    unsigned r0   = (A0 >> b) & 1u;
    unsigned r1   = (A1 >> b) & 1u;
    unsigned mags = (r1 * 0x3F800000u) | (r0 * 0x3F80u);
    unsigned t0   = __builtin_amdgcn_alignbit(S0, S0, (unsigned)r15) & 0x8000u;
    unsigned t1   = __builtin_amdgcn_alignbit(S1, S1, (unsigned)r31) & 0x80000000u;
    return mags | t0 | t1;
}

// Truncate two fp32 (raw bits) to one dword of two packed bf16.
__device__ __forceinline__ unsigned pack_bf16(unsigned hi, unsigned lo) {
    return __builtin_amdgcn_perm(hi, lo, 0x07060302u);
}

template<int KSPLIT, bool ATOMIC>
__global__ __launch_bounds__(512, 4)
void pass1(const unsigned* __restrict__ x32,   // fp32 bits [32][4096]
           const unsigned* __restrict__ Bnz,
           const unsigned* __restrict__ Bsg,
           float* __restrict__ partial)        // [KSPLIT][32][N] or out[32][N] if ATOMIC
{
    constexpr int KT  = K_DIM / KSPLIT;
    constexpr int NCH = KT / KCH;

    __shared__ unsigned bsm[2][2][NT_WORDS][BROW]; // [buf][plane][word][k]  ~33.8 KB
    __shared__ unsigned xsm[2][2048];              // [buf] 32 rows x 128 bf16, swizzled 16B granules

    const int nb = blockIdx.x;            // 0..31  N-tile
    const int kb = blockIdx.y;            // 0..KSPLIT-1
    const int w0 = nb * NT_WORDS;
    const int k0 = kb * KT;
    const int tid = threadIdx.x;

    // staging roles
    const int sk  = tid >> 2;             // B: k within chunk (0..127)
    const int swg = tid & 3;              // B: word group (4 words each)
    const int xr  = tid >> 4;             // x: row (0..31)
    const int xg  = tid & 15;             // x: 16B granule (0..15)
    const int xslot = (xg ^ (xr & 15)) << 2;   // swizzled dword slot

    uint4v nzr, sgr, xa, xb;              // reg-staged chunk (issue-early / write-late)

    auto sload = [&](int c) {
        const size_t kc = (size_t)(k0 + c * KCH);
        nzr = *(const uint4v*)(Bnz + (kc + sk) * WORDS_N + w0 + swg * 4);
        sgr = *(const uint4v*)(Bsg + (kc + sk) * WORDS_N + w0 + swg * 4);
        xa  = *(const uint4v*)(x32 + (size_t)xr * K_DIM + kc + xg * 8);
        xb  = *(const uint4v*)(x32 + (size_t)xr * K_DIM + kc + xg * 8 + 4);
    };
    auto swrite = [&](int buf) {
        #pragma unroll
        for (int j = 0; j < 4; ++j) {
            bsm[buf][0][swg * 4 + j][sk] = nzr[j];
            bsm[buf][1][swg * 4 + j][sk] = sgr[j];
        }
        uint4v pk;
        pk[0] = pack_bf16(xa[1], xa[0]);
        pk[1] = pack_bf16(xa[3], xa[2]);
        pk[2] = pack_bf16(xb[1], xb[0]);
        pk[3] = pack_bf16(xb[3], xb[2]);
        *(uint4v*)&xsm[buf][xr * 64 + xslot] = pk;
    };

    const int lane = tid & 63;
    const int wv   = tid >> 6;            // wave 0..7 owns 64 columns
    const int h    = lane >> 5;           // k-half
    const int b    = lane & 31;           // column within 32-tile == bit position
    const int r15  = (b + 17) & 31;
    const int r31  = (b + 1) & 31;

    f32x16 acc0{}, acc1{};

    sload(0); swrite(0);
    __syncthreads();

    for (int c = 0; c < NCH; ++c) {
        if (c + 1 < NCH) sload(c + 1);    // issue next-chunk loads early

        const int buf = c & 1;
        #pragma unroll 2
        for (int kk = 0; kk < KCH; kk += 16) {
            const int kf = kk + h * 8;    // frag k-base within chunk
            short8 af = *(const short8*)&xsm[buf][b * 64 + ((((kk >> 3) + h) ^ (b & 15)) << 2)];

            #pragma unroll
            for (int nt = 0; nt < 2; ++nt) {
                const unsigned* nzrow = &bsm[buf][0][wv * 2 + nt][kf];
                const unsigned* sgrow = &bsm[buf][1][wv * 2 + nt][kf];
                uint4v nzA = *(const uint4v*)nzrow;
                uint4v nzB = *(const uint4v*)(nzrow + 4);
                uint4v sgA = *(const uint4v*)sgrow;
                uint4v sgB = *(const uint4v*)(sgrow + 4);
                union { unsigned u[4]; short8 v; } bbv;
                bbv.u[0] = dec2(nzA[0], nzA[1], sgA[0], sgA[1], b, r15, r31);
                bbv.u[1] = dec2(nzA[2], nzA[3], sgA[2], sgA[3], b, r15, r31);
                bbv.u[2] = dec2(nzB[0], nzB[1], sgB[0], sgB[1], b, r15, r31);
                bbv.u[3] = dec2(nzB[2], nzB[3], sgB[2], sgB[3], b, r15, r31);
                if (nt == 0) acc0 = __builtin_amdgcn_mfma_f32_32x32x16_bf16(af, bbv.v, acc0, 0, 0, 0);
                else         acc1 = __builtin_amdgcn_mfma_f32_32x32x16_bf16(af, bbv.v, acc1, 0, 0, 0);
            }
        }
        if (c + 1 < NCH) swrite((c + 1) & 1);  // land next chunk after compute
        __syncthreads();
    }

    // Epilogue: per-wave 32x64 partial tile.
    // C/D layout: col = lane&31, row = (r&3) + 8*(r>>2) + 4*(lane>>5)
    const int col0 = nb * 512 + wv * 64 + b;
    #pragma unroll
    for (int r = 0; r < 16; ++r) {
        const int row = (r & 3) + 8 * (r >> 2) + 4 * h;
        if (ATOMIC) {
            atomicAdd(&partial[(size_t)row * N_DIM + col0],      acc0[r]);
            atomicAdd(&partial[(size_t)row * N_DIM + col0 + 32], acc1[r]);
        } else {
            const size_t base = ((size_t)(kb * 32 + row)) * N_DIM + col0;
            partial[base]      = acc0[r];
            partial[base + 32] = acc1[r];
        }
    }
}

template<int KSPLIT>
__global__ __launch_bounds__(256)
void pass2(const float* __restrict__ partial, const float* __restrict__ bias,
           float* __restrict__ out)
{
    const int gid = blockIdx.x * 256 + threadIdx.x;    // one float2 each
    const int m   = gid >> 13;
    const int n2  = gid & 8191;
    const size_t off = (size_t)m * N_DIM + (size_t)n2 * 2;
    float sx = 0.f, sy = 0.f;
    #pragma unroll
    for (int s = 0; s < KSPLIT; ++s) {
        const float2 p = *(const float2*)(partial + (size_t)s * 32 * N_DIM + off);
        sx += p.x; sy += p.y;
    }
    const float2 bv = *(const float2*)(bias + (size_t)n2 * 2);
    float2 y;
    y.x = sx + bv.x; y.x = y.x < 0.f ? 0.f : y.x;
    y.y = sy + bv.y; y.y = y.y < 0.f ? 0.f : y.y;
    *(float2*)(out + off) = y;
}

__global__ __launch_bounds__(256)
void bias_relu_inplace(const float* __restrict__ bias, float* __restrict__ out)
{
    const int gid = blockIdx.x * 256 + threadIdx.x;
    const int n2  = gid & 8191;
    const size_t off = (size_t)(gid >> 13) * N_DIM + (size_t)n2 * 2;
    const float2 p  = *(const float2*)(out + off);
    const float2 bv = *(const float2*)(bias + (size_t)n2 * 2);
    float2 y;
    y.x = p.x + bv.x; y.x = y.x < 0.f ? 0.f : y.x;
    y.y = p.y + bv.y; y.y = y.y < 0.f ? 0.f : y.y;
    *(float2*)(out + off) = y;
}

__global__ __launch_bounds__(256)
void zero_f32(float* __restrict__ p)
{
    p[blockIdx.x * 256 + threadIdx.x] = 0.f;
}

extern "C" void kernel_launch(void* const* d_in, const int* in_sizes, int n_in,
                              void* d_out, int out_size, void* d_ws, size_t ws_size,
                              hipStream_t stream) {
    const unsigned* x32 = (const unsigned*)d_in[0];   // fp32 bits
    const unsigned* nz  = (const unsigned*)d_in[1];
    const unsigned* sg  = (const unsigned*)d_in[2];
    const float* bias   = (const float*)d_in[3];
    float* out          = (float*)d_out;
    float* ws           = (float*)d_ws;

    const size_t need16 = (size_t)16 * 32 * N_DIM * 4;   // 32 MB
    const size_t need8  = need16 / 2;                    // 16 MB

    if (ws_size >= need16) {
        pass1<16, false><<<dim3(32, 16), 512, 0, stream>>>(x32, nz, sg, ws);
        pass2<16><<<1024, 256, 0, stream>>>(ws, bias, out);
    } else if (ws_size >= need8) {
        pass1<8, false><<<dim3(32, 8), 512, 0, stream>>>(x32, nz, sg, ws);
        pass2<8><<<1024, 256, 0, stream>>>(ws, bias, out);
    } else {
        zero_f32<<<2048, 256, 0, stream>>>(out);
        pass1<16, true><<<dim3(32, 16), 512, 0, stream>>>(x32, nz, sg, out);
        bias_relu_inplace<<<1024, 256, 0, stream>>>(bias, out);
    }
}

// Round 4
// 31.822 us; speedup vs baseline: 1.5602x; 1.1025x over previous
//
#include <hip/hip_runtime.h>
#include <hip/hip_bf16.h>

typedef __attribute__((ext_vector_type(8)))  short    short8;
typedef __attribute__((ext_vector_type(16))) float    f32x16;
typedef __attribute__((ext_vector_type(4)))  unsigned uint4v;
typedef __attribute__((ext_vector_type(2)))  unsigned uint2v;

#define K_DIM    4096
#define N_DIM    16384
#define WORDS_N  512
#define NT_WORDS 16      // 512 output columns per block
#define KCH      64      // k-chunk staged per double-buffer step
#define BROW     68      // padded LDS row stride for B planes (words)

// Decode two ternary weights (bit b of words A0/A1 = nonzero, S0/S1 = sign)
// into one dword of two packed bf16 {-1,0,+1}. nz=0,sg=1 -> -0.0 (harmless).
__device__ __forceinline__ unsigned dec2(unsigned A0, unsigned A1,
                                         unsigned S0, unsigned S1,
                                         int b, int r15, int r31) {
    unsigned r0   = (A0 >> b) & 1u;
    unsigned r1   = (A1 >> b) & 1u;
    unsigned mags = (r1 * 0x3F800000u) | (r0 * 0x3F80u);
    unsigned t0   = __builtin_amdgcn_alignbit(S0, S0, (unsigned)r15) & 0x8000u;
    unsigned t1   = __builtin_amdgcn_alignbit(S1, S1, (unsigned)r31) & 0x80000000u;
    return mags | t0 | t1;
}

// Truncate two fp32 (raw bits) to one dword of two packed bf16.
__device__ __forceinline__ unsigned pack_bf16(unsigned hi, unsigned lo) {
    return __builtin_amdgcn_perm(hi, lo, 0x07060302u);
}

template<int KSPLIT, bool ATOMIC>
__global__ __launch_bounds__(512, 4)
void pass1(const unsigned* __restrict__ x32,   // fp32 bits [32][4096]
           const unsigned* __restrict__ Bnz,
           const unsigned* __restrict__ Bsg,
           float* __restrict__ partial)        // [KSPLIT][32][N] or out[32][N] if ATOMIC
{
    constexpr int KT  = K_DIM / KSPLIT;
    constexpr int NCH = KT / KCH;

    __shared__ unsigned bsm[2][2][NT_WORDS][BROW]; // [buf][plane][word][k]  ~34.8 KB
    __shared__ unsigned xsm[2][1024];              // [buf] 32 rows x 64 bf16 (128B rows), swizzled

    const int nb = blockIdx.x;            // 0..31  N-tile
    const int kb = blockIdx.y;            // 0..KSPLIT-1
    const int w0 = nb * NT_WORDS;
    const int k0 = kb * KT;
    const int tid = threadIdx.x;

    // B staging roles: 64 k-rows x 2 planes x 4 quads = 512 threads, 16B each
    const int sk  = tid >> 3;             // k within chunk (0..63)
    const int spl = (tid >> 2) & 1;       // plane
    const int sq  = tid & 3;              // word quad (4 words)
    const unsigned* bsrc = spl ? Bsg : Bnz;
    // x staging roles: 32 rows x 16 threads x 4 fp32 = 8KB fp32 -> 4KB bf16
    const int xr  = tid >> 4;             // row (0..31)
    const int xg  = (tid & 15) >> 1;      // 16B-granule of bf16 row (0..7)
    const int xh  = tid & 1;              // which half of the granule
    const int xslot = xr * 32 + ((xg ^ (xr & 7)) << 2) + xh * 2;

    uint4v br, xa;                        // reg-staged chunk (issue-early / write-late)

    auto sload = [&](int c) {
        const size_t kc = (size_t)(k0 + c * KCH);
        br = *(const uint4v*)(bsrc + (kc + sk) * WORDS_N + w0 + sq * 4);
        xa = *(const uint4v*)(x32 + (size_t)xr * K_DIM + kc + (size_t)(tid & 15) * 4);
    };
    auto swrite = [&](int buf) {
        #pragma unroll
        for (int j = 0; j < 4; ++j)
            bsm[buf][spl][sq * 4 + j][sk] = br[j];
        uint2v pk;
        pk[0] = pack_bf16(xa[1], xa[0]);
        pk[1] = pack_bf16(xa[3], xa[2]);
        *(uint2v*)&xsm[buf][xslot] = pk;
    };

    const int lane = tid & 63;
    const int wv   = tid >> 6;            // wave 0..7 owns 2 word-columns
    const int h    = lane >> 5;           // k-half of the MFMA fragment
    const int b    = lane & 31;           // bit position == column within 32-tile
    const int r15  = (b + 17) & 31;
    const int r31  = (b + 1) & 31;

    f32x16 acc0{}, acc1{};

    sload(0); swrite(0);
    __syncthreads();

    for (int c = 0; c < NCH; ++c) {
        if (c + 1 < NCH) sload(c + 1);    // issue next-chunk loads early

        const int buf = c & 1;
        #pragma unroll
        for (int kk = 0; kk < KCH; kk += 16) {
            const int kf = kk + h * 8;    // frag k-base within chunk
            const int g  = (kk >> 3) + h; // x granule index 0..7
            short8 af = *(const short8*)&xsm[buf][b * 32 + ((g ^ (b & 7)) << 2)];

            #pragma unroll
            for (int nt = 0; nt < 2; ++nt) {
                const unsigned* nzrow = &bsm[buf][0][wv * 2 + nt][kf];
                const unsigned* sgrow = &bsm[buf][1][wv * 2 + nt][kf];
                uint4v nzA = *(const uint4v*)nzrow;
                uint4v nzB = *(const uint4v*)(nzrow + 4);
                uint4v sgA = *(const uint4v*)sgrow;
                uint4v sgB = *(const uint4v*)(sgrow + 4);
                union { unsigned u[4]; short8 v; } bbv;
                bbv.u[0] = dec2(nzA[0], nzA[1], sgA[0], sgA[1], b, r15, r31);
                bbv.u[1] = dec2(nzA[2], nzA[3], sgA[2], sgA[3], b, r15, r31);
                bbv.u[2] = dec2(nzB[0], nzB[1], sgB[0], sgB[1], b, r15, r31);
                bbv.u[3] = dec2(nzB[2], nzB[3], sgB[2], sgB[3], b, r15, r31);
                if (nt == 0) acc0 = __builtin_amdgcn_mfma_f32_32x32x16_bf16(af, bbv.v, acc0, 0, 0, 0);
                else         acc1 = __builtin_amdgcn_mfma_f32_32x32x16_bf16(af, bbv.v, acc1, 0, 0, 0);
            }
        }
        if (c + 1 < NCH) swrite((c + 1) & 1);  // land next chunk after compute
        __syncthreads();
    }

    // Epilogue: per-wave 32x64 partial tile.
    // C/D layout: col = lane&31, row = (r&3) + 8*(r>>2) + 4*(lane>>5)
    const int col0 = nb * 512 + wv * 64 + b;
    #pragma unroll
    for (int r = 0; r < 16; ++r) {
        const int row = (r & 3) + 8 * (r >> 2) + 4 * h;
        if (ATOMIC) {
            atomicAdd(&partial[(size_t)row * N_DIM + col0],      acc0[r]);
            atomicAdd(&partial[(size_t)row * N_DIM + col0 + 32], acc1[r]);
        } else {
            const size_t base = ((size_t)(kb * 32 + row)) * N_DIM + col0;
            partial[base]      = acc0[r];
            partial[base + 32] = acc1[r];
        }
    }
}

template<int KSPLIT>
__global__ __launch_bounds__(256)
void pass2(const float* __restrict__ partial, const float* __restrict__ bias,
           float* __restrict__ out)
{
    const int gid = blockIdx.x * 256 + threadIdx.x;    // one float2 each
    const int m   = gid >> 13;
    const int n2  = gid & 8191;
    const size_t off = (size_t)m * N_DIM + (size_t)n2 * 2;
    float sx = 0.f, sy = 0.f;
    #pragma unroll
    for (int s = 0; s < KSPLIT; ++s) {
        const float2 p = *(const float2*)(partial + (size_t)s * 32 * N_DIM + off);
        sx += p.x; sy += p.y;
    }
    const float2 bv = *(const float2*)(bias + (size_t)n2 * 2);
    float2 y;
    y.x = sx + bv.x; y.x = y.x < 0.f ? 0.f : y.x;
    y.y = sy + bv.y; y.y = y.y < 0.f ? 0.f : y.y;
    *(float2*)(out + off) = y;
}

__global__ __launch_bounds__(256)
void bias_relu_inplace(const float* __restrict__ bias, float* __restrict__ out)
{
    const int gid = blockIdx.x * 256 + threadIdx.x;
    const int n2  = gid & 8191;
    const size_t off = (size_t)(gid >> 13) * N_DIM + (size_t)n2 * 2;
    const float2 p  = *(const float2*)(out + off);
    const float2 bv = *(const float2*)(bias + (size_t)n2 * 2);
    float2 y;
    y.x = p.x + bv.x; y.x = y.x < 0.f ? 0.f : y.x;
    y.y = p.y + bv.y; y.y = y.y < 0.f ? 0.f : y.y;
    *(float2*)(out + off) = y;
}

__global__ __launch_bounds__(256)
void zero_f32(float* __restrict__ p)
{
    p[blockIdx.x * 256 + threadIdx.x] = 0.f;
}

extern "C" void kernel_launch(void* const* d_in, const int* in_sizes, int n_in,
                              void* d_out, int out_size, void* d_ws, size_t ws_size,
                              hipStream_t stream) {
    const unsigned* x32 = (const unsigned*)d_in[0];   // fp32 bits
    const unsigned* nz  = (const unsigned*)d_in[1];
    const unsigned* sg  = (const unsigned*)d_in[2];
    const float* bias   = (const float*)d_in[3];
    float* out          = (float*)d_out;
    float* ws           = (float*)d_ws;

    const size_t need16 = (size_t)16 * 32 * N_DIM * 4;   // 32 MB
    const size_t need8  = need16 / 2;                    // 16 MB

    if (ws_size >= need16) {
        pass1<16, false><<<dim3(32, 16), 512, 0, stream>>>(x32, nz, sg, ws);
        pass2<16><<<1024, 256, 0, stream>>>(ws, bias, out);
    } else if (ws_size >= need8) {
        pass1<8, false><<<dim3(32, 8), 512, 0, stream>>>(x32, nz, sg, ws);
        pass2<8><<<1024, 256, 0, stream>>>(ws, bias, out);
    } else {
        zero_f32<<<2048, 256, 0, stream>>>(out);
        pass1<16, true><<<dim3(32, 16), 512, 0, stream>>>(x32, nz, sg, out);
        bias_relu_inplace<<<1024, 256, 0, stream>>>(bias, out);
    }
}

// Round 5
// 30.457 us; speedup vs baseline: 1.6301x; 1.0448x over previous
//
#include <hip/hip_runtime.h>
#include <hip/hip_bf16.h>

typedef __attribute__((ext_vector_type(8)))  short    short8;
typedef __attribute__((ext_vector_type(16))) float    f32x16;
typedef __attribute__((ext_vector_type(4)))  unsigned uint4v;
typedef __attribute__((ext_vector_type(2)))  unsigned uint2v;

#define K_DIM    4096
#define N_DIM    16384
#define WORDS_N  512
#define NT_WORDS 8       // 256 output columns per block
#define KCH      64      // k-chunk staged per double-buffer step
#define BROW     68      // padded LDS row stride for B planes (words)

// Decode two ternary weights (bit b of words A0/A1 = nonzero, S0/S1 = sign)
// into one dword of two packed bf16 {-1,0,+1}. nz=0,sg=1 -> -0.0 (harmless).
__device__ __forceinline__ unsigned dec2(unsigned A0, unsigned A1,
                                         unsigned S0, unsigned S1,
                                         int b, int r15, int r31) {
    unsigned r0   = (A0 >> b) & 1u;
    unsigned r1   = (A1 >> b) & 1u;
    unsigned mags = (r1 * 0x3F800000u) | (r0 * 0x3F80u);
    unsigned t0   = __builtin_amdgcn_alignbit(S0, S0, (unsigned)r15) & 0x8000u;
    unsigned t1   = __builtin_amdgcn_alignbit(S1, S1, (unsigned)r31) & 0x80000000u;
    return mags | t0 | t1;
}

// Truncate two fp32 (raw bits) to one dword of two packed bf16.
__device__ __forceinline__ unsigned pack_bf16(unsigned hi, unsigned lo) {
    return __builtin_amdgcn_perm(hi, lo, 0x07060302u);
}

template<int KSPLIT, bool ATOMIC>
__global__ __launch_bounds__(512, 4)
void pass1(const unsigned* __restrict__ x32,   // fp32 bits [32][4096]
           const unsigned* __restrict__ Bnz,
           const unsigned* __restrict__ Bsg,
           float* __restrict__ partial)        // [KSPLIT][32][N] or out[32][N] if ATOMIC
{
    constexpr int KT  = K_DIM / KSPLIT;
    constexpr int NCH = KT / KCH;
    constexpr int NNB = WORDS_N / NT_WORDS;    // 64 N-tiles

    __shared__ unsigned bsm[2][2][NT_WORDS][BROW]; // [buf][plane][word][k]  ~8.5 KB
    __shared__ unsigned xsm[2][1024];              // [buf] 32 rows x 64 bf16, swizzled granules

    // Flat bid decode keeping the two nb-blocks that share each 64B B-sector
    // on the same XCD (XCD = bid&7 = nb>>3), all kb for an nb-group too:
    // per-XCD B footprint = 16MB/8 = 2MB <= 4MB L2.
    const int bid = blockIdx.x;
    const int nb  = (bid & 7) * 8 + ((bid >> 3) & 7);   // 0..63
    const int kb  = bid >> 6;                           // 0..KSPLIT-1 (KSPLIT=8)
    const int w0  = nb * NT_WORDS;
    const int k0  = kb * KT;
    const int tid = threadIdx.x;

    // B staging roles: 64 k-rows x 2 planes x 4 word-pairs, 8B per thread
    const int sk  = tid >> 3;             // k within chunk (0..63)
    const int spl = (tid >> 2) & 1;       // plane
    const int wp  = tid & 3;              // word pair
    const unsigned* bsrc = spl ? Bsg : Bnz;
    // x staging roles: 32 rows x 16 threads x 4 fp32 = 8KB fp32 -> 4KB bf16
    const int xr  = tid >> 4;             // row (0..31)
    const int xg  = (tid & 15) >> 1;      // 16B-granule of bf16 row (0..7)
    const int xh  = tid & 1;              // which half of the granule
    const int xslot = xr * 32 + ((xg ^ (xr & 7)) << 2) + xh * 2;

    uint2v br;                            // reg-staged chunk (issue-early / write-late)
    uint4v xa;

    auto sload = [&](int c) {
        const size_t kc = (size_t)(k0 + c * KCH);
        br = *(const uint2v*)(bsrc + (kc + sk) * WORDS_N + w0 + wp * 2);
        xa = *(const uint4v*)(x32 + (size_t)xr * K_DIM + kc + (size_t)(tid & 15) * 4);
    };
    auto swrite = [&](int buf) {
        bsm[buf][spl][wp * 2][sk]     = br[0];
        bsm[buf][spl][wp * 2 + 1][sk] = br[1];
        uint2v pk;
        pk[0] = pack_bf16(xa[1], xa[0]);
        pk[1] = pack_bf16(xa[3], xa[2]);
        *(uint2v*)&xsm[buf][xslot] = pk;
    };

    const int lane = tid & 63;
    const int wv   = tid >> 6;            // wave 0..7 owns word-column w0+wv
    const int h    = lane >> 5;           // k-half of the MFMA fragment
    const int b    = lane & 31;           // bit position == column within 32-tile
    const int r15  = (b + 17) & 31;
    const int r31  = (b + 1) & 31;

    f32x16 acc{};

    sload(0); swrite(0);
    __syncthreads();

    for (int c = 0; c < NCH; ++c) {
        if (c + 1 < NCH) sload(c + 1);    // issue next-chunk loads early

        const int buf = c & 1;
        #pragma unroll
        for (int kk = 0; kk < KCH; kk += 16) {
            const int kf = kk + h * 8;    // frag k-base within chunk
            const int g  = (kk >> 3) + h; // x granule index 0..7
            short8 af = *(const short8*)&xsm[buf][b * 32 + ((g ^ (b & 7)) << 2)];

            const unsigned* nzrow = &bsm[buf][0][wv][kf];
            const unsigned* sgrow = &bsm[buf][1][wv][kf];
            uint4v nzA = *(const uint4v*)nzrow;
            uint4v nzB = *(const uint4v*)(nzrow + 4);
            uint4v sgA = *(const uint4v*)sgrow;
            uint4v sgB = *(const uint4v*)(sgrow + 4);
            union { unsigned u[4]; short8 v; } bbv;
            bbv.u[0] = dec2(nzA[0], nzA[1], sgA[0], sgA[1], b, r15, r31);
            bbv.u[1] = dec2(nzA[2], nzA[3], sgA[2], sgA[3], b, r15, r31);
            bbv.u[2] = dec2(nzB[0], nzB[1], sgB[0], sgB[1], b, r15, r31);
            bbv.u[3] = dec2(nzB[2], nzB[3], sgB[2], sgB[3], b, r15, r31);
            acc = __builtin_amdgcn_mfma_f32_32x32x16_bf16(af, bbv.v, acc, 0, 0, 0);
        }
        if (c + 1 < NCH) swrite((c + 1) & 1);  // land next chunk after compute
        __syncthreads();
    }

    // Epilogue: per-wave 32x32 partial tile.
    // C/D layout: col = lane&31, row = (r&3) + 8*(r>>2) + 4*(lane>>5)
    const int col0 = nb * (NT_WORDS * 32) + wv * 32 + b;
    #pragma unroll
    for (int r = 0; r < 16; ++r) {
        const int row = (r & 3) + 8 * (r >> 2) + 4 * h;
        if (ATOMIC) {
            atomicAdd(&partial[(size_t)row * N_DIM + col0], acc[r]);
        } else {
            partial[((size_t)(kb * 32 + row)) * N_DIM + col0] = acc[r];
        }
    }
}

template<int KSPLIT>
__global__ __launch_bounds__(256)
void pass2(const float* __restrict__ partial, const float* __restrict__ bias,
           float* __restrict__ out)
{
    const int gid = blockIdx.x * 256 + threadIdx.x;    // one float2 each
    const int m   = gid >> 13;
    const int n2  = gid & 8191;
    const size_t off = (size_t)m * N_DIM + (size_t)n2 * 2;
    float sx = 0.f, sy = 0.f;
    #pragma unroll
    for (int s = 0; s < KSPLIT; ++s) {
        const float2 p = *(const float2*)(partial + (size_t)s * 32 * N_DIM + off);
        sx += p.x; sy += p.y;
    }
    const float2 bv = *(const float2*)(bias + (size_t)n2 * 2);
    float2 y;
    y.x = sx + bv.x; y.x = y.x < 0.f ? 0.f : y.x;
    y.y = sy + bv.y; y.y = y.y < 0.f ? 0.f : y.y;
    *(float2*)(out + off) = y;
}

__global__ __launch_bounds__(256)
void bias_relu_inplace(const float* __restrict__ bias, float* __restrict__ out)
{
    const int gid = blockIdx.x * 256 + threadIdx.x;
    const int n2  = gid & 8191;
    const size_t off = (size_t)(gid >> 13) * N_DIM + (size_t)n2 * 2;
    const float2 p  = *(const float2*)(out + off);
    const float2 bv = *(const float2*)(bias + (size_t)n2 * 2);
    float2 y;
    y.x = p.x + bv.x; y.x = y.x < 0.f ? 0.f : y.x;
    y.y = p.y + bv.y; y.y = y.y < 0.f ? 0.f : y.y;
    *(float2*)(out + off) = y;
}

__global__ __launch_bounds__(256)
void zero_f32(float* __restrict__ p)
{
    p[blockIdx.x * 256 + threadIdx.x] = 0.f;
}

extern "C" void kernel_launch(void* const* d_in, const int* in_sizes, int n_in,
                              void* d_out, int out_size, void* d_ws, size_t ws_size,
                              hipStream_t stream) {
    const unsigned* x32 = (const unsigned*)d_in[0];   // fp32 bits
    const unsigned* nz  = (const unsigned*)d_in[1];
    const unsigned* sg  = (const unsigned*)d_in[2];
    const float* bias   = (const float*)d_in[3];
    float* out          = (float*)d_out;
    float* ws           = (float*)d_ws;

    const size_t need8 = (size_t)8 * 32 * N_DIM * 4;   // 16 MB

    if (ws_size >= need8) {
        pass1<8, false><<<512, 512, 0, stream>>>(x32, nz, sg, ws);
        pass2<8><<<1024, 256, 0, stream>>>(ws, bias, out);
    } else {
        zero_f32<<<2048, 256, 0, stream>>>(out);
        pass1<8, true><<<512, 512, 0, stream>>>(x32, nz, sg, out);
        bias_relu_inplace<<<1024, 256, 0, stream>>>(bias, out);
    }
}